// Round 1
// baseline (376.142 us; speedup 1.0000x reference)
//
#include <hip/hip_runtime.h>
#include <cstdint>
#include <cstddef>

#define Bn 64
#define Hn 56
#define Wn 56
#define Cn 256
#define COn 64
#define RWn 64                       // route width = 256/4
#define XSZ ((size_t)Bn * Hn * Wn * RWn)   // 12,845,056 floats

// ---------------------------------------------------------------------------
// Kernel A: per-(batch, row-split) partial bin sums.
// S[b,kh,kw,ci] = sum over (ho,wo) of in[b, 2ho+kh, 2wo+kw, ci].
// Row h feeds kh=0 iff (h even && h<=52), kh=1 iff (h odd && h<=53),
// kh=2 iff (h even && 2<=h<=54). Same pattern for columns. h==55/w==55 unused.
// Block: 256 threads = 4 waves; wave k handles pixel w%4==k, lane handles
// channels 4*lane..4*lane+3 -> float4 loads, 1KB/wave per instruction.
// ---------------------------------------------------------------------------
__global__ __launch_bounds__(256) void kA_bins(
        const float* __restrict__ in, float* __restrict__ spart,
        int NS, int RPS) {
    const int blk   = blockIdx.x;
    const int b     = blk / NS;
    const int split = blk - b * NS;
    const int tid   = threadIdx.x;
    const int lane  = tid & 63;
    const int wave  = tid >> 6;

    const float* base = in + (size_t)b * (Hn * Wn * Cn) + lane * 4;

    float4 acc[9];
#pragma unroll
    for (int k = 0; k < 9; ++k) acc[k] = make_float4(0.f, 0.f, 0.f, 0.f);

    const int h0 = split * RPS;
    for (int h = h0; h < h0 + RPS; ++h) {
        const bool he  = (h & 1) == 0;
        const float rh0 = (he  && h <= 52)            ? 1.f : 0.f;
        const float rh1 = (!he && h <= 53)            ? 1.f : 0.f;
        const float rh2 = (he  && h >= 2 && h <= 54)  ? 1.f : 0.f;
        if (rh0 == 0.f && rh1 == 0.f && rh2 == 0.f) continue;  // h == 55 (wave-uniform)
        const float* rowp = base + (size_t)h * (Wn * Cn);
#pragma unroll
        for (int wb = 0; wb < Wn; wb += 4) {
            const int w = wb + wave;
            const float4 v = *(const float4*)(rowp + (size_t)w * Cn);
            const bool we  = (w & 1) == 0;
            const float cw0 = (we  && w <= 52)           ? 1.f : 0.f;
            const float cw1 = (!we && w <= 53)           ? 1.f : 0.f;
            const float cw2 = (we  && w >= 2 && w <= 54) ? 1.f : 0.f;
            const float wt[9] = { rh0*cw0, rh0*cw1, rh0*cw2,
                                  rh1*cw0, rh1*cw1, rh1*cw2,
                                  rh2*cw0, rh2*cw1, rh2*cw2 };
#pragma unroll
            for (int k = 0; k < 9; ++k) {   // static unroll -> register accumulators
                acc[k].x += v.x * wt[k];
                acc[k].y += v.y * wt[k];
                acc[k].z += v.z * wt[k];
                acc[k].w += v.w * wt[k];
            }
        }
    }

    // reduce the 4 waves' partials (same channels, different pixels) via LDS
    __shared__ float4 lds4[4][9][64];     // 36 KB
#pragma unroll
    for (int k = 0; k < 9; ++k) lds4[wave][k][lane] = acc[k];  // contiguous b128
    __syncthreads();

    const float* ldsf = (const float*)lds4;
    float* op = spart + (((size_t)b * NS + split) * 9) * 256;
#pragma unroll
    for (int k = 0; k < 9; ++k) {
        const float s = ldsf[(0 * 9 + k) * 256 + tid] + ldsf[(1 * 9 + k) * 256 + tid]
                      + ldsf[(2 * 9 + k) * 256 + tid] + ldsf[(3 * 9 + k) * 256 + tid];
        op[k * 256 + tid] = s;             // coalesced
    }
}

// ---------------------------------------------------------------------------
// Kernel B: one block per batch. Reduce splits -> S[9][256], contract with
// conv_w (HWIO -> index (bin*256+ci)*64+co), /729 + conv_b, dense logits,
// first-occurrence argmax -> route[b].
// ---------------------------------------------------------------------------
__global__ __launch_bounds__(256) void kB_logits(
        const float* __restrict__ spart,
        const float* __restrict__ convw, const float* __restrict__ convb,
        const float* __restrict__ fcw,   const float* __restrict__ fcb,
        float* __restrict__ out_logits, int* __restrict__ routes, int NS) {
    const int b = blockIdx.x;
    const int t = threadIdx.x;
    __shared__ float sS[9 * 256];
    __shared__ float pP[4][64];
    __shared__ float pld[64];
    __shared__ float lgt[4];

    // reduce split partials (coalesced)
    for (int k = 0; k < 9; ++k) {
        float a = 0.f;
        for (int s = 0; s < NS; ++s)
            a += spart[(((size_t)b * NS + s) * 9 + k) * 256 + t];
        sS[k * 256 + t] = a;
    }
    __syncthreads();

    // contraction: part = t>>6 handles 64 input channels, co = t&63
    {
        const int co = t & 63, part = t >> 6;
        float a = 0.f;
        for (int k = 0; k < 9; ++k) {
            const int cb = part * 64;
#pragma unroll 8
            for (int ci = 0; ci < 64; ++ci)
                a += sS[k * 256 + cb + ci] * convw[(size_t)(k * 256 + cb + ci) * 64 + co];
        }
        pP[part][co] = a;
    }
    __syncthreads();

    if (t < 64) {
        pld[t] = (pP[0][t] + pP[1][t] + pP[2][t] + pP[3][t]) * (1.f / 729.f) + convb[t];
    }
    __syncthreads();

    if (t < 4) {
        float a = fcb[t];
#pragma unroll
        for (int co = 0; co < 64; ++co) a += pld[co] * fcw[co * 4 + t];
        lgt[t] = a;
        out_logits[b * 4 + t] = a;
    }
    __syncthreads();

    if (t == 0) {
        int bi = 0; float best = lgt[0];
#pragma unroll
        for (int r = 1; r < 4; ++r) if (lgt[r] > best) { best = lgt[r]; bi = r; }
        routes[b] = bi;
    }
}

// ---------------------------------------------------------------------------
// Kernel C: routed channel-group gather. One float4 per thread.
// total float4 = 64*56*56*16 = 3,211,264 = 12544 blocks * 256 threads.
// ---------------------------------------------------------------------------
__global__ __launch_bounds__(256) void kC_gather(
        const float* __restrict__ in, const int* __restrict__ routes,
        float* __restrict__ out) {
    const size_t idx = (size_t)blockIdx.x * 256 + threadIdx.x;  // float4 index
    const size_t pix = idx >> 4;
    const int   f4i  = (int)(idx & 15);
    const int   b    = (int)(pix / (Hn * Wn));
    const int   r    = routes[b];
    const float4 v = *(const float4*)(in + pix * (size_t)Cn + (size_t)r * RWn + (size_t)f4i * 4);
    ((float4*)out)[idx] = v;
}

extern "C" void kernel_launch(void* const* d_in, const int* in_sizes, int n_in,
                              void* d_out, int out_size, void* d_ws, size_t ws_size,
                              hipStream_t stream) {
    const float* in    = (const float*)d_in[0];
    const float* convw = (const float*)d_in[1];
    const float* convb = (const float*)d_in[2];
    const float* fcw   = (const float*)d_in[3];
    const float* fcb   = (const float*)d_in[4];
    float* out = (float*)d_out;

    // pick the largest row-split count (divisor of 56) the workspace can hold
    int NS = 1;
    const int cand[5] = {14, 8, 4, 2, 1};
    for (int i = 0; i < 5; ++i) {
        const size_t need = (size_t)Bn * cand[i] * 9 * 256 * sizeof(float) + 256;
        if (ws_size >= need) { NS = cand[i]; break; }
    }
    const int RPS = Hn / NS;

    float* spart = (float*)d_ws;
    int* routes  = (int*)((char*)d_ws + (size_t)Bn * NS * 9 * 256 * sizeof(float));

    kA_bins  <<<Bn * NS, 256, 0, stream>>>(in, spart, NS, RPS);
    kB_logits<<<Bn,      256, 0, stream>>>(spart, convw, convb, fcw, fcb,
                                           out + XSZ, routes, NS);
    kC_gather<<<12544,   256, 0, stream>>>(in, routes, out);
}

// Round 2
// 361.447 us; speedup vs baseline: 1.0407x; 1.0407x over previous
//
#include <hip/hip_runtime.h>
#include <cstdint>
#include <cstddef>

#define Bn 64
#define Hn 56
#define Wn 56
#define Cn 256
#define COn 64
#define RWn 64                              // route width = 256/4
#define XSZ ((size_t)Bn * Hn * Wn * RWn)    // 12,845,056 floats

__device__ __forceinline__ void f4add(float4& a, const float4& v) {
    a.x += v.x; a.y += v.y; a.z += v.z; a.w += v.w;
}
__device__ __forceinline__ float4 f4sub(const float4& a, const float4& b) {
    return make_float4(a.x - b.x, a.y - b.y, a.z - b.z, a.w - b.w);
}
__device__ __forceinline__ void f4fma(float4& a, float s, const float4& v) {
    a.x += s * v.x; a.y += s * v.y; a.z += s * v.z; a.w += s * v.w;
}

// ---------------------------------------------------------------------------
// Kernel A: per-(batch, row-split) partial bin sums.
// S[b,kh,kw,ci] = sum over (ho,wo) of in[b, 2ho+kh, 2wo+kw, ci].
// Row h feeds kh=0 iff (h even, h<=52), kh=1 iff (h odd, h<=53),
// kh=2 iff (h even, 2<=h<=54); h==55 unused. Same pattern for columns.
//
// Within a wave, w = wb + wave has FIXED parity, so each wave's pixels all
// belong to the same column-bin parity class:
//   wave0 (w=0,4..52, even): kw0 gets all; kw2 gets all but w=0.
//   wave2 (w=2,6..54, even): kw2 gets all; kw0 gets all but w=54.
//   wave1 (w=1,5..53, odd):  kw1 gets all.
//   wave3 (w=3,7..55, odd):  kw1 gets all but w=55 (we skip that load).
// So per load: 4 adds into a single row-sum R; per row: <=6 float4 FMAs
// (wave-uniform branches). VALU/load ~7 instrs vs HBM feed ~100 cyc/KB.
// ---------------------------------------------------------------------------
__global__ __launch_bounds__(256) void kA_bins(
        const float* __restrict__ in, float* __restrict__ spart,
        int NS, int RPS) {
    const int blk   = blockIdx.x;
    const int b     = blk / NS;
    const int split = blk - b * NS;
    const int tid   = threadIdx.x;
    const int lane  = tid & 63;
    const int wave  = tid >> 6;

    const float* base = in + (size_t)b * (Hn * Wn * Cn) + (size_t)lane * 4
                           + (size_t)wave * Cn;

    float4 acc[9];
#pragma unroll
    for (int k = 0; k < 9; ++k) acc[k] = make_float4(0.f, 0.f, 0.f, 0.f);

    const int h0 = split * RPS;
    for (int h = h0; h < h0 + RPS; ++h) {
        const bool  he  = (h & 1) == 0;
        const float rh0 = (he  && h <= 52)           ? 1.f : 0.f;
        const float rh1 = (!he && h <= 53)           ? 1.f : 0.f;
        const float rh2 = (he  && h >= 2 && h <= 54) ? 1.f : 0.f;
        if (rh0 == 0.f && rh1 == 0.f && rh2 == 0.f) continue;   // h == 55

        const float* rowp = base + (size_t)h * (Wn * Cn);
        float4 R  = make_float4(0.f, 0.f, 0.f, 0.f);
        float4 e0 = R, e1 = R;   // edge pixels: w==0 (wave0), w==54 (wave2)
#pragma unroll
        for (int wb = 0; wb < Wn; wb += 4) {
            if (wb == 52 && wave == 3) continue;    // w==55 never used (uniform)
            const float4 v = *(const float4*)(rowp + (size_t)wb * Cn);
            if (wb == 0)  e0 = v;
            if (wb == 52) e1 = v;
            f4add(R, v);
        }

        const float rhE[3] = { rh0, rh1, rh2 };
        if ((wave & 1) == 0) {          // wave-uniform: no divergence
            float4 cA, cB;              // contributions to kw=0, kw=2
            if (wave == 0) { cA = R;            cB = f4sub(R, e0); }
            else           { cA = f4sub(R, e1); cB = R;            }
#pragma unroll
            for (int kh = 0; kh < 3; ++kh) {
                f4fma(acc[kh * 3 + 0], rhE[kh], cA);
                f4fma(acc[kh * 3 + 2], rhE[kh], cB);
            }
        } else {                        // kw=1 from odd waves
#pragma unroll
            for (int kh = 0; kh < 3; ++kh)
                f4fma(acc[kh * 3 + 1], rhE[kh], R);
        }
    }

    // reduce the 4 waves' partials (same channels, different pixels) via LDS
    __shared__ float4 lds4[4][9][64];     // 36 KB
#pragma unroll
    for (int k = 0; k < 9; ++k) lds4[wave][k][lane] = acc[k];  // contiguous b128
    __syncthreads();

    const float* ldsf = (const float*)lds4;
    float* op = spart + (((size_t)b * NS + split) * 9) * 256;
#pragma unroll
    for (int k = 0; k < 9; ++k) {
        const float s = ldsf[(0 * 9 + k) * 256 + tid] + ldsf[(1 * 9 + k) * 256 + tid]
                      + ldsf[(2 * 9 + k) * 256 + tid] + ldsf[(3 * 9 + k) * 256 + tid];
        op[k * 256 + tid] = s;             // coalesced
    }
}

// ---------------------------------------------------------------------------
// Kernel B: one block per batch. Reduce splits -> S[9][256], contract with
// conv_w (HWIO -> index (bin*256+ci)*64+co), /729 + conv_b, dense logits,
// first-occurrence argmax -> route[b].
// ---------------------------------------------------------------------------
__global__ __launch_bounds__(256) void kB_logits(
        const float* __restrict__ spart,
        const float* __restrict__ convw, const float* __restrict__ convb,
        const float* __restrict__ fcw,   const float* __restrict__ fcb,
        float* __restrict__ out_logits, int* __restrict__ routes, int NS) {
    const int b = blockIdx.x;
    const int t = threadIdx.x;
    __shared__ float sS[9 * 256];
    __shared__ float pP[4][64];
    __shared__ float pld[64];
    __shared__ float lgt[4];

    // reduce split partials (coalesced; 9 independent accumulation chains)
#pragma unroll
    for (int k = 0; k < 9; ++k) {
        float a = 0.f;
#pragma unroll 7
        for (int s = 0; s < NS; ++s)
            a += spart[(((size_t)b * NS + s) * 9 + k) * 256 + t];
        sS[k * 256 + t] = a;
    }
    __syncthreads();

    // contraction: part = t>>6 handles 64 input channels, co = t&63
    {
        const int co = t & 63, part = t >> 6;
        float a = 0.f;
#pragma unroll
        for (int k = 0; k < 9; ++k) {
            const int cb = part * 64;
#pragma unroll 8
            for (int ci = 0; ci < 64; ++ci)
                a += sS[k * 256 + cb + ci] * convw[(size_t)(k * 256 + cb + ci) * 64 + co];
        }
        pP[part][co] = a;
    }
    __syncthreads();

    if (t < 64) {
        pld[t] = (pP[0][t] + pP[1][t] + pP[2][t] + pP[3][t]) * (1.f / 729.f) + convb[t];
    }
    __syncthreads();

    if (t < 4) {
        float a = fcb[t];
#pragma unroll
        for (int co = 0; co < 64; ++co) a += pld[co] * fcw[co * 4 + t];
        lgt[t] = a;
        out_logits[b * 4 + t] = a;
    }
    __syncthreads();

    if (t == 0) {
        int bi = 0; float best = lgt[0];
#pragma unroll
        for (int r = 1; r < 4; ++r) if (lgt[r] > best) { best = lgt[r]; bi = r; }
        routes[b] = bi;
    }
}

// ---------------------------------------------------------------------------
// Kernel C: routed channel-group gather. One float4 per thread.
// total float4 = 64*56*56*16 = 3,211,264 = 12544 blocks * 256 threads.
// ---------------------------------------------------------------------------
__global__ __launch_bounds__(256) void kC_gather(
        const float* __restrict__ in, const int* __restrict__ routes,
        float* __restrict__ out) {
    const size_t idx = (size_t)blockIdx.x * 256 + threadIdx.x;  // float4 index
    const size_t pix = idx >> 4;
    const int   f4i  = (int)(idx & 15);
    const int   b    = (int)(pix / (Hn * Wn));
    const int   r    = routes[b];
    const float4 v = *(const float4*)(in + pix * (size_t)Cn + (size_t)r * RWn + (size_t)f4i * 4);
    ((float4*)out)[idx] = v;
}

extern "C" void kernel_launch(void* const* d_in, const int* in_sizes, int n_in,
                              void* d_out, int out_size, void* d_ws, size_t ws_size,
                              hipStream_t stream) {
    const float* in    = (const float*)d_in[0];
    const float* convw = (const float*)d_in[1];
    const float* convb = (const float*)d_in[2];
    const float* fcw   = (const float*)d_in[3];
    const float* fcb   = (const float*)d_in[4];
    float* out = (float*)d_out;

    // pick the largest row-split count (divisor of 56) the workspace can hold
    int NS = 1;
    const int cand[5] = {14, 8, 4, 2, 1};
    for (int i = 0; i < 5; ++i) {
        const size_t need = (size_t)Bn * cand[i] * 9 * 256 * sizeof(float) + 256;
        if (ws_size >= need) { NS = cand[i]; break; }
    }
    const int RPS = Hn / NS;

    float* spart = (float*)d_ws;
    int* routes  = (int*)((char*)d_ws + (size_t)Bn * NS * 9 * 256 * sizeof(float));

    kA_bins  <<<Bn * NS, 256, 0, stream>>>(in, spart, NS, RPS);
    kB_logits<<<Bn,      256, 0, stream>>>(spart, convw, convb, fcw, fcb,
                                           out + XSZ, routes, NS);
    kC_gather<<<12544,   256, 0, stream>>>(in, routes, out);
}